// Round 1
// baseline (2005.557 us; speedup 1.0000x reference)
//
#include <hip/hip_runtime.h>
#include <stdint.h>

// BiDense: y[b,s,f] = 0.25*bx[b,s]*bk[f]*(K - 2*popcount(xbits^kbits)) + bias[f]
// bx = maxabs over D per (b,s) + eps ; bk = maxabs over D per f + eps.
// Signs packed to bits; ±1 GEMM done as XNOR-popcount (integer exact).

#define M_ROWS 8192      // B*S
#define D_DIM  4096      // K
#define F_DIM  16384     // N
#define KW     128       // D_DIM/32 words
#define F32_EPS 1.1920928955078125e-7f

// ---------------- pass 1a: pack x signs + row maxabs ----------------
__global__ __launch_bounds__(256) void pack_x(const float* __restrict__ x,
                                              uint32_t* __restrict__ xbits,
                                              float* __restrict__ bx) {
    const int row  = blockIdx.x;
    const int tid  = threadIdx.x;
    const int lane = tid & 63;
    const int wv   = tid >> 6;
    const float* xr = x + (size_t)row * D_DIM;
    float mv = 0.f;
#pragma unroll
    for (int it = 0; it < 16; ++it) {
        float v = xr[it * 256 + tid];
        mv = fmaxf(mv, fabsf(v));
        unsigned long long m = __ballot(v >= 0.f);
        if (lane == 0) {
            uint2 wp = make_uint2((uint32_t)m, (uint32_t)(m >> 32));
            *(uint2*)&xbits[(size_t)row * KW + 2 * (it * 4 + wv)] = wp;
        }
    }
#pragma unroll
    for (int off = 32; off > 0; off >>= 1)
        mv = fmaxf(mv, __shfl_down(mv, off, 64));
    __shared__ float sm[4];
    if (lane == 0) sm[wv] = mv;
    __syncthreads();
    if (tid == 0) {
        float m4 = fmaxf(fmaxf(sm[0], sm[1]), fmaxf(sm[2], sm[3]));
        bx[row] = m4 + F32_EPS;
    }
}

// ---------------- pass 1b: pack kernel signs (per column f) + partial col maxabs ----
// grid (64, 16): x -> 256-col group, y -> 256-row (d) segment
__global__ __launch_bounds__(256) void pack_k(const float* __restrict__ kern,
                                              uint32_t* __restrict__ kbits,
                                              float* __restrict__ bkpart) {
    const int f   = blockIdx.x * 256 + threadIdx.x;
    const int seg = blockIdx.y;
    const int d0  = seg * 256;
    const float* kp = kern + (size_t)d0 * F_DIM + f;
    float mv = 0.f;
    uint32_t words[8];
#pragma unroll
    for (int wq = 0; wq < 8; ++wq) {
        uint32_t wrd = 0;
#pragma unroll
        for (int b = 0; b < 32; ++b) {
            float v = kp[(size_t)(wq * 32 + b) * F_DIM];
            mv = fmaxf(mv, fabsf(v));
            wrd |= (v >= 0.f ? 1u : 0u) << b;
        }
        words[wq] = wrd;
    }
    uint4* dst = (uint4*)&kbits[(size_t)f * KW + seg * 8];
    dst[0] = make_uint4(words[0], words[1], words[2], words[3]);
    dst[1] = make_uint4(words[4], words[5], words[6], words[7]);
    bkpart[seg * F_DIM + f] = mv;
}

// ---------------- pass 1c: reduce partial maxabs -> 0.25*(max+eps) ----------------
__global__ __launch_bounds__(256) void reduce_bk(const float* __restrict__ bkpart,
                                                 float* __restrict__ bkq) {
    const int f = blockIdx.x * 256 + threadIdx.x;
    float m = 0.f;
#pragma unroll
    for (int seg = 0; seg < 16; ++seg)
        m = fmaxf(m, bkpart[seg * F_DIM + f]);
    bkq[f] = 0.25f * (m + F32_EPS);
}

// ---------------- pass 2: XNOR-popcount GEMM ----------------
// block = 256 thr, tile 128x128, per-thread 8x8 (rows tm+16i, cols tn+16j).
// LDS pad 36 words/row: x-reads 2-way bank alias (free), k-reads conflict-free,
// rows stay 16B-aligned for b128.
#define KT  32
#define LDP 36
__global__ __launch_bounds__(256, 4) void bgemm(const uint32_t* __restrict__ xbits,
                                                const uint32_t* __restrict__ kbits,
                                                const float* __restrict__ bx,
                                                const float* __restrict__ bkq,
                                                const float* __restrict__ bias,
                                                float* __restrict__ out) {
    __shared__ uint32_t xs[128 * LDP];
    __shared__ uint32_t ks[128 * LDP];
    const int tid = threadIdx.x;
    const int m0 = blockIdx.y * 128;
    const int n0 = blockIdx.x * 128;
    const int tm = tid & 15;
    const int tn = tid >> 4;
    const int srow = tid >> 1;
    const int ssub = tid & 1;
    int acc[8][8] = {};

    for (int it = 0; it < 4; ++it) {
        const int wbase = it * KT;
        const uint32_t* gx = xbits + (size_t)(m0 + srow) * KW + wbase + ssub * 16;
        const uint32_t* gk = kbits + (size_t)(n0 + srow) * KW + wbase + ssub * 16;
        uint32_t* lx = &xs[srow * LDP + ssub * 16];
        uint32_t* lk = &ks[srow * LDP + ssub * 16];
#pragma unroll
        for (int q = 0; q < 4; ++q) {
            uint4 vx = *(const uint4*)&gx[q * 4];
            uint4 vk = *(const uint4*)&gk[q * 4];
            *(uint4*)&lx[q * 4] = vx;
            *(uint4*)&lk[q * 4] = vk;
        }
        __syncthreads();
#pragma unroll
        for (int ch = 0; ch < 8; ++ch) {
            uint4 xa[8];
#pragma unroll
            for (int i = 0; i < 8; ++i)
                xa[i] = *(const uint4*)&xs[(tm + 16 * i) * LDP + ch * 4];
#pragma unroll
            for (int j = 0; j < 8; ++j) {
                uint4 kb = *(const uint4*)&ks[(tn + 16 * j) * LDP + ch * 4];
#pragma unroll
                for (int i = 0; i < 8; ++i) {
                    acc[i][j] += __popc(xa[i].x ^ kb.x) + __popc(xa[i].y ^ kb.y)
                               + __popc(xa[i].z ^ kb.z) + __popc(xa[i].w ^ kb.w);
                }
            }
        }
        __syncthreads();
    }

    float bxv[8];
#pragma unroll
    for (int i = 0; i < 8; ++i) bxv[i] = bx[m0 + tm + 16 * i];
#pragma unroll
    for (int j = 0; j < 8; ++j) {
        const int col = n0 + tn + 16 * j;
        const float s  = bkq[col];
        const float bz = bias[col];
#pragma unroll
        for (int i = 0; i < 8; ++i) {
            const int row = m0 + tm + 16 * i;
            out[(size_t)row * F_DIM + col] =
                bxv[i] * s * (float)(D_DIM - 2 * acc[i][j]) + bz;
        }
    }
}

extern "C" void kernel_launch(void* const* d_in, const int* in_sizes, int n_in,
                              void* d_out, int out_size, void* d_ws, size_t ws_size,
                              hipStream_t stream) {
    const float* x    = (const float*)d_in[0];
    const float* kern = (const float*)d_in[1];
    const float* bias = (const float*)d_in[2];
    float* out = (float*)d_out;

    uint8_t* ws = (uint8_t*)d_ws;
    // ws layout (≈13.1 MiB total)
    uint32_t* xbits  = (uint32_t*)ws;                          // 4 MiB
    uint32_t* kbits  = (uint32_t*)(ws + 4194304);              // 8 MiB
    float*    bx     = (float*)(ws + 12582912);                // 32 KiB
    float*    bkq    = (float*)(ws + 12615680);                // 64 KiB
    float*    bkpart = (float*)(ws + 12681216);                // 1 MiB

    pack_x   <<<M_ROWS, 256, 0, stream>>>(x, xbits, bx);
    pack_k   <<<dim3(64, 16), 256, 0, stream>>>(kern, kbits, bkpart);
    reduce_bk<<<64, 256, 0, stream>>>(bkpart, bkq);
    bgemm    <<<dim3(F_DIM / 128, M_ROWS / 128), 256, 0, stream>>>(
                 xbits, kbits, bx, bkq, bias, out);
}